// Round 1
// baseline (1197.842 us; speedup 1.0000x reference)
//
#include <hip/hip_runtime.h>
#include <hip/hip_bf16.h>

typedef __bf16 bf16x8 __attribute__((ext_vector_type(8)));
typedef __bf16 bf16x4 __attribute__((ext_vector_type(4)));
typedef float  f32x4  __attribute__((ext_vector_type(4)));

#define N_PTS  65536
#define B_SZ   4
#define P_TOT  (B_SZ * N_PTS)
#define PITCH1 104   // 96 k (67 padded) + 8 pad, bf16 elems: breaks b128 bank aliasing
#define PITCH2 136   // 128 k + 8 pad

// ---------------------------------------------------------------------------
// Kernel 1: fused 2-layer bf16-MFMA MLP + general grid head -> gx,gy in ws
// Block = 256 thr (4 waves), 64 points. Wave w owns output-channel tiles
// {2w, 2w+1} (16 rows each); weights live in register fragments.
// MFMA 16x16x32 layouts (HW-verified per guide):
//   A: lane holds A[lane&15][(lane>>4)*8 + j]
//   B: lane holds B[(lane>>4)*8 + j][lane&15]
//   D: lane holds D[(lane>>4)*4 + r][lane&15]
// ---------------------------------------------------------------------------
__global__ __launch_bounds__(256) void mlp_grid_kernel(
    const float* __restrict__ x_loc, const float* __restrict__ x_feat,
    const float* __restrict__ W1, const float* __restrict__ b1,
    const float* __restrict__ W2, const float* __restrict__ b2,
    const float* __restrict__ Wr, const float* __restrict__ br,
    float* __restrict__ grid_out)
{
    __shared__ __bf16 stage[64 * PITCH1];   // h0 tile, [pt][k] bf16
    __shared__ __bf16 h1s[64 * PITCH2];     // h1 tile, [pt][k] bf16
    __shared__ float  gpart[16][2][64];     // grid partials [wave*4+q][o][pt]

    const int tid = threadIdx.x;
    const int w   = tid >> 6;
    const int l   = tid & 63;
    const int q   = l >> 4;
    const int lp  = l & 15;
    const int pt0 = blockIdx.x * 64;

    // ---- weight fragments into registers (once) ----
    bf16x8 w1f[2][3];
    bf16x8 w2f[2][4];
    float  b1v[2][4], b2v[2][4], wrp[2][2][4];
    for (int i = 0; i < 2; ++i) {
        const int o = (2 * w + i) * 16 + lp;
        for (int ks = 0; ks < 3; ++ks) {
            const int k0 = ks * 32 + q * 8;
            bf16x8 a;
            #pragma unroll
            for (int j = 0; j < 8; ++j) {
                const int k = k0 + j;
                const float v = (k < 67) ? W1[o * 67 + k] : 0.0f;
                a[j] = (__bf16)v;
            }
            w1f[i][ks] = a;
        }
        for (int ks = 0; ks < 4; ++ks) {
            const int k0 = ks * 32 + q * 8;
            bf16x8 a;
            #pragma unroll
            for (int j = 0; j < 8; ++j) a[j] = (__bf16)W2[o * 128 + k0 + j];
            w2f[i][ks] = a;
        }
        const int ob = (2 * w + i) * 16 + q * 4;
        #pragma unroll
        for (int r = 0; r < 4; ++r) {
            b1v[i][r]    = b1[ob + r];
            b2v[i][r]    = b2[ob + r];
            wrp[0][i][r] = Wr[0 * 131 + 3 + ob + r];
            wrp[1][i][r] = Wr[1 * 131 + 3 + ob + r];
        }
    }

    // ---- stage h0 = concat(x_loc, x_feat) -> LDS bf16 [pt][k] ----
    {
        const int kk = tid >> 6;   // 0..3
        const int pt = tid & 63;
        const int p  = pt0 + pt;
        const int b  = p >> 16;
        const int n  = p & 0xFFFF;
        for (int kb = 0; kb < 68; kb += 4) {
            const int k = kb + kk;
            if (k < 67) {
                const float v = (k < 3) ? x_loc[((b * 3 + k) << 16) | n]
                                        : x_feat[((b * 64 + (k - 3)) << 16) | n];
                stage[pt * PITCH1 + k] = (__bf16)v;
            }
        }
        for (int k = 67 + kk; k < 96; k += 4) stage[pt * PITCH1 + k] = (__bf16)0.0f;
    }
    __syncthreads();

    // ---- layer 1: h1 = relu(W1 h0 + b1), write bf16 to LDS ----
    for (int col = 0; col < 4; ++col) {
        const int pt = col * 16 + lp;
        bf16x8 bfr[3];
        #pragma unroll
        for (int ks = 0; ks < 3; ++ks)
            bfr[ks] = *(const bf16x8*)&stage[pt * PITCH1 + ks * 32 + q * 8];
        #pragma unroll
        for (int i = 0; i < 2; ++i) {
            f32x4 acc = {0.f, 0.f, 0.f, 0.f};
            #pragma unroll
            for (int ks = 0; ks < 3; ++ks)
                acc = __builtin_amdgcn_mfma_f32_16x16x32_bf16(w1f[i][ks], bfr[ks], acc, 0, 0, 0);
            bf16x4 hv;
            #pragma unroll
            for (int r = 0; r < 4; ++r)
                hv[r] = (__bf16)fmaxf(acc[r] + b1v[i][r], 0.0f);
            *(bf16x4*)&h1s[pt * PITCH2 + (2 * w + i) * 16 + q * 4] = hv;
        }
    }
    __syncthreads();

    // ---- layer 2 + grid partials ----
    for (int col = 0; col < 4; ++col) {
        const int pt = col * 16 + lp;
        bf16x8 bfr[4];
        #pragma unroll
        for (int ks = 0; ks < 4; ++ks)
            bfr[ks] = *(const bf16x8*)&h1s[pt * PITCH2 + ks * 32 + q * 8];
        float p0 = 0.f, p1 = 0.f;
        #pragma unroll
        for (int i = 0; i < 2; ++i) {
            f32x4 acc = {0.f, 0.f, 0.f, 0.f};
            #pragma unroll
            for (int ks = 0; ks < 4; ++ks)
                acc = __builtin_amdgcn_mfma_f32_16x16x32_bf16(w2f[i][ks], bfr[ks], acc, 0, 0, 0);
            #pragma unroll
            for (int r = 0; r < 4; ++r) {
                const float v = fmaxf(acc[r] + b2v[i][r], 0.0f);
                p0 += wrp[0][i][r] * v;
                p1 += wrp[1][i][r] * v;
            }
        }
        gpart[w * 4 + q][0][pt] = p0;
        gpart[w * 4 + q][1][pt] = p1;
    }
    __syncthreads();

    // ---- final grid reduce: grid[o] = br[o] + Wr[:, :3] x_loc + partials ----
    if (tid < 128) {
        const int o  = tid >> 6;
        const int pt = tid & 63;
        const int p  = pt0 + pt;
        const int b  = p >> 16;
        const int n  = p & 0xFFFF;
        float s = br[o];
        #pragma unroll
        for (int c = 0; c < 3; ++c)
            s += Wr[o * 131 + c] * x_loc[((b * 3 + c) << 16) | n];
        #pragma unroll
        for (int g = 0; g < 16; ++g) s += gpart[g][o][pt];
        grid_out[o * P_TOT + p] = s;
    }
}

// ---------------------------------------------------------------------------
// Kernel 2: bilinear sampling of m0/m1/m2 at (gx,gy), out (B,448,N) fp32.
// One thread per point; loops 448 channels; 4 scalar gathers/channel
// (L1/L2-served: touched slice region ~21 KB), coalesced NT stores.
// Block = 1024 pts so the per-channel slice working set is reused 4096x.
// ---------------------------------------------------------------------------
__global__ __launch_bounds__(1024) void sample_kernel(
    const float* __restrict__ m0, const float* __restrict__ m1,
    const float* __restrict__ m2, const float* __restrict__ grid,
    float* __restrict__ out)
{
    const int p = blockIdx.x * 1024 + threadIdx.x;
    const int b = p >> 16;
    const int n = p & 0xFFFF;
    const float gx = grid[p];
    const float gy = grid[P_TOT + p];

    float ix = ((gx + 1.0f) * 128.0f - 1.0f) * 0.5f;
    float iy = ((gy + 1.0f) * 128.0f - 1.0f) * 0.5f;
    ix = fminf(fmaxf(ix, 0.0f), 127.0f);
    iy = fminf(fmaxf(iy, 0.0f), 127.0f);
    const float x0f = floorf(ix);
    const float y0f = floorf(iy);
    const float wx = ix - x0f;
    const float wy = iy - y0f;
    const int x0 = (int)x0f, y0 = (int)y0f;
    const int x1 = min(x0 + 1, 127);
    const int y1 = min(y0 + 1, 127);
    const int o00 = y0 * 128 + x0;
    const int o01 = y0 * 128 + x1;
    const int o10 = y1 * 128 + x0;
    const int o11 = y1 * 128 + x1;
    const float w00 = (1.f - wy) * (1.f - wx);
    const float w01 = (1.f - wy) * wx;
    const float w10 = wy * (1.f - wx);
    const float w11 = wy * wx;

    const float* s0 = m0 + (size_t)(b * 64)  * 16384;
    const float* s1 = m1 + (size_t)(b * 128) * 16384;
    const float* s2 = m2 + (size_t)(b * 256) * 16384;
    float* op = out + (size_t)(b * 448) * 65536 + n;

    #pragma unroll 4
    for (int c = 0; c < 64; ++c) {
        const float v = w00 * s0[o00] + w01 * s0[o01] + w10 * s0[o10] + w11 * s0[o11];
        __builtin_nontemporal_store(v, op);
        s0 += 16384; op += 65536;
        if ((c & 15) == 15) __syncthreads();   // keep waves phase-locked for L1 reuse
    }
    #pragma unroll 4
    for (int c = 0; c < 128; ++c) {
        const float v = w00 * s1[o00] + w01 * s1[o01] + w10 * s1[o10] + w11 * s1[o11];
        __builtin_nontemporal_store(v, op);
        s1 += 16384; op += 65536;
        if ((c & 15) == 15) __syncthreads();
    }
    #pragma unroll 4
    for (int c = 0; c < 256; ++c) {
        const float v = w00 * s2[o00] + w01 * s2[o01] + w10 * s2[o10] + w11 * s2[o11];
        __builtin_nontemporal_store(v, op);
        s2 += 16384; op += 65536;
        if ((c & 15) == 15) __syncthreads();
    }
}

extern "C" void kernel_launch(void* const* d_in, const int* in_sizes, int n_in,
                              void* d_out, int out_size, void* d_ws, size_t ws_size,
                              hipStream_t stream)
{
    (void)in_sizes; (void)n_in; (void)out_size; (void)ws_size;
    const float* x_loc  = (const float*)d_in[0];
    const float* x_feat = (const float*)d_in[1];
    const float* m0     = (const float*)d_in[2];
    const float* m1     = (const float*)d_in[3];
    const float* m2     = (const float*)d_in[4];
    const float* W1     = (const float*)d_in[5];
    const float* b1     = (const float*)d_in[6];
    const float* W2     = (const float*)d_in[7];
    const float* b2     = (const float*)d_in[8];
    const float* Wr     = (const float*)d_in[9];
    const float* br     = (const float*)d_in[10];
    float* out  = (float*)d_out;
    float* grid = (float*)d_ws;   // gx at [0,P), gy at [P,2P) — 2 MB

    mlp_grid_kernel<<<dim3(P_TOT / 64), dim3(256), 0, stream>>>(
        x_loc, x_feat, W1, b1, W2, b2, Wr, br, grid);
    sample_kernel<<<dim3(P_TOT / 1024), dim3(1024), 0, stream>>>(
        m0, m1, m2, grid, out);
}